// Round 7
// baseline (53.445 us; speedup 1.0000x reference)
//
#include <hip/hip_runtime.h>
#include <stdint.h>

// Problem constants (match reference)
#define BB 8
#define SS 4096
#define TOKEN_BITS 12
#define EMB 1024
#define NB 12
#define TABLE 4096
#define POS_BITS 13
#define NROWS (BB * SS)          // 32768 (b,s) rows

typedef float f32x4 __attribute__((ext_vector_type(4)));

// ---------------------------------------------------------------------------
// Kernel 1 (R3 verbatim): build remapT[n][pat-bits] — pattern-packed remap.
// ---------------------------------------------------------------------------
__global__ __launch_bounds__(256) void build_remapT(const float* __restrict__ tables,
                                                    const int* __restrict__ conn,
                                                    uint64_t* __restrict__ remapT) {
    __shared__ float row[TABLE];
    __shared__ int csh[NB];
    const int n = blockIdx.x;
    const int t = threadIdx.x;
    if (t < NB) csh[t] = conn[n * NB + t];
    const f32x4* src = (const f32x4*)(tables + (size_t)n * TABLE);
    f32x4* dst = (f32x4*)row;
#pragma unroll
    for (int i = 0; i < 4; ++i)
        dst[t + 256 * i] = src[t + 256 * i];
    __syncthreads();
    int cr[NB];
#pragma unroll
    for (int j = 0; j < NB; ++j) cr[j] = csh[j];
    for (int base = 0; base < TABLE; base += 256) {
        int pat = base + t;
        int addr = 0;
#pragma unroll
        for (int j = 0; j < NB; ++j)
            addr = (addr << 1) | ((pat >> cr[j]) & 1);   // j=0 is MSB (reference order)
        uint64_t m = __ballot(row[addr] != 0.0f);
        if ((t & 63) == 0)
            remapT[(size_t)n * (TABLE / 64) + (pat >> 6)] = m;
    }
}

// ---------------------------------------------------------------------------
// Kernel 2 (R3 verbatim): bit-transpose remapT -> remap[pat][neuron-bits].
// ---------------------------------------------------------------------------
__global__ __launch_bounds__(256) void transpose_remap(const uint32_t* __restrict__ remapT32,
                                                       uint32_t* __restrict__ remap32) {
    const int w   = blockIdx.x >> 4;                       // 0..31
    const int pat = ((blockIdx.x & 15) << 8) | threadIdx.x;
    const int wordIdx = pat >> 5;
    const int bit     = pat & 31;
    uint32_t res = 0;
#pragma unroll
    for (int i = 0; i < 32; ++i) {
        int n = 32 * w + i;
        res |= ((remapT32[(size_t)n * (TABLE / 32) + wordIdx] >> bit) & 1u) << i;
    }
    remap32[(size_t)pat * (EMB / 32) + w] = res;
}

// ---------------------------------------------------------------------------
// Bucketing: group the 32768 rows by their 12-bit pattern so the embed kernel
// loads each remap row once per bucket instead of once per row.
// ---------------------------------------------------------------------------
__global__ void zero_hist(uint32_t* __restrict__ hist) {
    hist[blockIdx.x * 256 + threadIdx.x] = 0;              // 16 blocks x 256 = 4096
}

__global__ __launch_bounds__(256) void pat_hist(const int* __restrict__ tokens,
                                                uint32_t* __restrict__ pats,
                                                uint32_t* __restrict__ hist) {
    const int r = blockIdx.x * 256 + threadIdx.x;          // 128 blocks
    const int* tp = tokens + (size_t)r * TOKEN_BITS;
    uint32_t p = 0;
#pragma unroll
    for (int j = 0; j < TOKEN_BITS; ++j)
        p |= (uint32_t)(tp[j] & 1) << j;
    pats[r] = p;
    atomicAdd(&hist[p], 1u);
}

// single block, 1024 threads: exclusive prefix sum of hist[4096] -> off[4097],
// plus cursor copy cur[] for the scatter pass.
__global__ __launch_bounds__(1024) void scan_offsets(const uint32_t* __restrict__ hist,
                                                     uint32_t* __restrict__ off,
                                                     uint32_t* __restrict__ cur) {
    __shared__ uint32_t sc[1024];
    const int t = threadIdx.x;
    uint32_t h[4];
#pragma unroll
    for (int k = 0; k < 4; ++k) h[k] = hist[4 * t + k];
    uint32_t s = h[0] + h[1] + h[2] + h[3];
    sc[t] = s;
    __syncthreads();
    for (int d = 1; d < 1024; d <<= 1) {
        uint32_t v = (t >= d) ? sc[t - d] : 0;
        __syncthreads();
        sc[t] += v;
        __syncthreads();
    }
    uint32_t excl = sc[t] - s;
#pragma unroll
    for (int k = 0; k < 4; ++k) {
        off[4 * t + k] = excl;
        cur[4 * t + k] = excl;
        excl += h[k];
    }
    if (t == 1023) off[4096] = sc[1023];
}

__global__ __launch_bounds__(256) void scatter_rows(const uint32_t* __restrict__ pats,
                                                    uint32_t* __restrict__ cur,
                                                    uint32_t* __restrict__ rowlist) {
    const int r = blockIdx.x * 256 + threadIdx.x;          // 128 blocks
    uint32_t p = pats[r];
    uint32_t idx = atomicAdd(&cur[p], 1u);
    rowlist[idx] = (uint32_t)r;
}

// ---------------------------------------------------------------------------
// Kernel 6: bucketed embed. One block per PATTERN. The remap word is loaded
// ONCE into registers; the inner loop is {uniform scalar rowlist load, ~12
// VALU, one coalesced f32x4 store} — no per-row dependent vector load.
// ---------------------------------------------------------------------------
__global__ __launch_bounds__(256) void ram_embed_bucket(const uint32_t* __restrict__ rowlist,
                                                        const uint32_t* __restrict__ off,
                                                        const uint32_t* __restrict__ remap,
                                                        float* __restrict__ out) {
    const int p = blockIdx.x;
    const uint32_t beg = off[p], end = off[p + 1];
    if (beg == end) return;
    const int t = threadIdx.x;

    const uint32_t word = remap[(size_t)p * (EMB / 32) + (t >> 3)];
    const uint32_t nib  = (word >> ((t & 7) * 4)) & 0xFu;

    const int n0 = t * 4;
    int sh[4];
#pragma unroll
    for (int u = 0; u < 4; ++u)
        sh[u] = POS_BITS - 1 - ((n0 + u) % POS_BITS);

    for (uint32_t i = beg; i < end; ++i) {
        const uint32_t r = rowlist[i];              // wave-uniform -> scalar load
        const int s = (int)(r & (SS - 1));
        uint32_t pn =  (uint32_t)((s >> sh[0]) & 1)
                    | ((uint32_t)((s >> sh[1]) & 1) << 1)
                    | ((uint32_t)((s >> sh[2]) & 1) << 2)
                    | ((uint32_t)((s >> sh[3]) & 1) << 3);
        uint32_t x = nib ^ pn;
        f32x4 o;
        o.x = (x & 1u) ? 1.0f : 0.0f;
        o.y = (x & 2u) ? 1.0f : 0.0f;
        o.z = (x & 4u) ? 1.0f : 0.0f;
        o.w = (x & 8u) ? 1.0f : 0.0f;
        *(f32x4*)(out + (size_t)r * EMB + n0) = o;
    }
}

// ---------------------------------------------------------------------------
extern "C" void kernel_launch(void* const* d_in, const int* in_sizes, int n_in,
                              void* d_out, int out_size, void* d_ws, size_t ws_size,
                              hipStream_t stream) {
    const int*   tokens = (const int*)d_in[0];
    const float* tables = (const float*)d_in[1];
    const int*   conn   = (const int*)d_in[2];
    float*       out    = (float*)d_out;

    // ws layout (uint32 units):
    // [0, 131072)        remapT   (512 KB, pattern-packed)
    // [131072, 262144)   remap32  (512 KB, neuron-packed)
    // [262144, 294912)   pats     (128 KB)
    // [294912, 299008)   hist     (16 KB)
    // [299008, 303112)   off      (4097 entries)
    // [303112, 307208)   cur      (4096 entries, padded start)
    // [307208, 339976)   rowlist  (128 KB)
    uint32_t* base    = (uint32_t*)d_ws;
    uint64_t* remapT  = (uint64_t*)base;
    uint32_t* remap32 = base + 131072;
    uint32_t* pats    = base + 262144;
    uint32_t* hist    = base + 294912;
    uint32_t* off     = base + 299008;
    uint32_t* cur     = base + 303112;
    uint32_t* rowlist = base + 307208;

    build_remapT<<<EMB, 256, 0, stream>>>(tables, conn, remapT);
    transpose_remap<<<(TABLE / 256) * (EMB / 32), 256, 0, stream>>>(
        (const uint32_t*)remapT, remap32);
    zero_hist<<<16, 256, 0, stream>>>(hist);
    pat_hist<<<NROWS / 256, 256, 0, stream>>>(tokens, pats, hist);
    scan_offsets<<<1, 1024, 0, stream>>>(hist, off, cur);
    scatter_rows<<<NROWS / 256, 256, 0, stream>>>(pats, cur, rowlist);
    ram_embed_bucket<<<TABLE, 256, 0, stream>>>(rowlist, off, remap32, out);
}